// Round 6
// baseline (192.883 us; speedup 1.0000x reference)
//
#include <hip/hip_runtime.h>
#include <cstdint>
#include <cstddef>

typedef _Float16 f16;
typedef f16 f16x8 __attribute__((ext_vector_type(8)));
typedef __fp16 fp16x2 __attribute__((ext_vector_type(2)));
typedef float f32x4 __attribute__((ext_vector_type(4)));
typedef float f32x16 __attribute__((ext_vector_type(16)));
typedef uint32_t u32;

// ---------------- helpers ----------------

__device__ __forceinline__ void gload16(const void* g, void* l) {
  __builtin_amdgcn_global_load_lds((const __attribute__((address_space(1))) void*)g,
                                   (__attribute__((address_space(3))) void*)l,
                                   16u, 0, 0u);
}

__device__ __forceinline__ u32 pkrtz(float a, float b) {
  union { fp16x2 v; u32 u; } t;
  t.v = __builtin_amdgcn_cvt_pkrtz(a, b);
  return t.u;
}

__device__ __forceinline__ u32 packh2(float a, float b) { return pkrtz(a, b); }

__device__ __forceinline__ float max3f(float a, float b, float c) {
  return fmaxf(fmaxf(a, b), c);
}

// exchange: a = {a.lo32lanes, b.lo32lanes}, b = {a.hi32lanes, b.hi32lanes}
__device__ __forceinline__ void pl32swap(u32& a, u32& b) {
  asm volatile("v_permlane32_swap_b32 %0, %1" : "+v"(a), "+v"(b));
}

// ---------------- fp32 -> fp16 convert ----------------

__global__ __launch_bounds__(256) void cvt_f32_f16(const float* __restrict__ in,
                                                   f16* __restrict__ out, int n) {
  int i = (blockIdx.x * 256 + threadIdx.x) * 8;
  if (i >= n) return;
  float4 a = *(const float4*)(in + i);
  float4 b = *(const float4*)(in + i + 4);
  f16x8 o;
  o[0] = (f16)a.x; o[1] = (f16)a.y; o[2] = (f16)a.z; o[3] = (f16)a.w;
  o[4] = (f16)b.x; o[5] = (f16)b.y; o[6] = (f16)b.z; o[7] = (f16)b.w;
  *(f16x8*)(out + i) = o;
}

// ---------------- bias factor tables ----------------
// U[t][2r] = log2e*cos(w_r t), U[t][2r+1] = log2e*sin(w_r t)   (2048 x 64)
// Wt[h][t][2r] = a*c - b*s, Wt[h][t][2r+1] = a*s + b*c         (16 x 2048 x 64)

__global__ __launch_bounds__(256) void build_tables(const float* __restrict__ alpha,
                                                    const float* __restrict__ beta,
                                                    f16* __restrict__ U,
                                                    f16* __restrict__ Wt) {
  int idx = blockIdx.x * 256 + threadIdx.x;   // t*32 + r
  int t = idx >> 5, r = idx & 31;
  float w = powf(10000.0f, -(float)r / 32.0f);
  float ang = w * (float)t;
  float c = cosf(ang), s = sinf(ang);
  const float L2E = 1.44269504089f;
  U[t * 64 + 2 * r]     = (f16)(c * L2E);
  U[t * 64 + 2 * r + 1] = (f16)(s * L2E);
  #pragma unroll
  for (int h = 0; h < 16; ++h) {
    float al = alpha[h * 32 + r], be = beta[h * 32 + r];
    Wt[(size_t)(h * 2048 + t) * 64 + 2 * r]     = (f16)(al * c - be * s);
    Wt[(size_t)(h * 2048 + t) * 64 + 2 * r + 1] = (f16)(al * s + be * c);
  }
}

// ---------------- GEMM1: qkv = X @ Wqkv^T, scatter into Q,K,Vt ----------------

__global__ __launch_bounds__(256) void gemm_qkv(const f16* __restrict__ A,
                                                const f16* __restrict__ B,
                                                f16* __restrict__ Q,
                                                f16* __restrict__ Kh,
                                                f16* __restrict__ Vt) {
  __shared__ __align__(16) char sm[32768];
  char* As = sm;
  char* Bs = sm + 16384;
  const int K = 1024;
  int tid = threadIdx.x;
  int lane = tid & 63, wid = tid >> 6;
  int bid = blockIdx.x;                      // 1536 blocks, XCD-chunked
  int id = (bid & 7) * 192 + (bid >> 3);
  int m0 = (id / 24) * 128, n0 = (id % 24) * 128;
  int wm = wid >> 1, wn = wid & 1;
  int c = lane & 15, g = lane >> 4, l7 = lane & 7;

  f32x4 acc[4][4] = {};

  for (int kt = 0; kt < K / 64; ++kt) {
    #pragma unroll
    for (int i = 0; i < 4; ++i) {
      int p = i * 4096 + tid * 16;
      int q = p ^ (((p >> 7) & 7) << 4);
      int row = q >> 7, ce = (q & 127) >> 1;
      gload16(A + (size_t)(m0 + row) * K + kt * 64 + ce, As + i * 4096 + wid * 1024);
      gload16(B + (size_t)(n0 + row) * K + kt * 64 + ce, Bs + i * 4096 + wid * 1024);
    }
    __syncthreads();
    #pragma unroll
    for (int kk = 0; kk < 2; ++kk) {
      int co = (kk * 64 + g * 16) ^ (l7 << 4);
      f16x8 af[4], bf[4];
      #pragma unroll
      for (int fr = 0; fr < 4; ++fr)
        af[fr] = *(const f16x8*)(As + (wm * 64 + fr * 16 + c) * 128 + co);
      #pragma unroll
      for (int fn = 0; fn < 4; ++fn)
        bf[fn] = *(const f16x8*)(Bs + (wn * 64 + fn * 16 + c) * 128 + co);
      #pragma unroll
      for (int fr = 0; fr < 4; ++fr)
        #pragma unroll
        for (int fn = 0; fn < 4; ++fn)
          acc[fr][fn] = __builtin_amdgcn_mfma_f32_16x16x32_f16(af[fr], bf[fn], acc[fr][fn], 0, 0, 0);
    }
    __syncthreads();
  }

  int which = n0 >> 10;
  #pragma unroll
  for (int fr = 0; fr < 4; ++fr) {
    int m = m0 + wm * 64 + fr * 16 + g * 4;
    int b = m >> 11, t = m & 2047;
    #pragma unroll
    for (int fn = 0; fn < 4; ++fn) {
      int n = n0 + wn * 64 + fn * 16 + c;
      int nf = n & 1023, hh = nf >> 6, d = nf & 63;
      if (which == 0) {
        #pragma unroll
        for (int r = 0; r < 4; ++r)
          Q[(size_t)((b * 16 + hh) * 2048 + (t + r)) * 64 + d] = (f16)(acc[fr][fn][r] * 0.180336880111f);
      } else if (which == 1) {
        #pragma unroll
        for (int r = 0; r < 4; ++r)
          Kh[(size_t)((b * 16 + hh) * 2048 + (t + r)) * 64 + d] = (f16)acc[fr][fn][r];
      } else {
        uint2 pk;
        pk.x = packh2(acc[fr][fn][0], acc[fr][fn][1]);
        pk.y = packh2(acc[fr][fn][2], acc[fr][fn][3]);
        *(uint2*)(Vt + (size_t)((b * 16 + hh) * 64 + d) * 2048 + t) = pk;
      }
    }
  }
}

// ---------------- GEMM2: out = AO @ Wout^T (fp32 out) ----------------

__global__ __launch_bounds__(256) void gemm_out(const f16* __restrict__ A,
                                                const f16* __restrict__ B,
                                                float* __restrict__ Cout) {
  __shared__ __align__(16) char sm[32768];
  char* As = sm;
  char* Bs = sm + 16384;
  const int K = 1024;
  int tid = threadIdx.x;
  int lane = tid & 63, wid = tid >> 6;
  int bid = blockIdx.x;                      // 512 blocks, XCD-chunked
  int id = (bid & 7) * 64 + (bid >> 3);
  int m0 = (id >> 3) * 128, n0 = (id & 7) * 128;
  int wm = wid >> 1, wn = wid & 1;
  int c = lane & 15, g = lane >> 4, l7 = lane & 7;

  f32x4 acc[4][4] = {};

  for (int kt = 0; kt < K / 64; ++kt) {
    #pragma unroll
    for (int i = 0; i < 4; ++i) {
      int p = i * 4096 + tid * 16;
      int q = p ^ (((p >> 7) & 7) << 4);
      int row = q >> 7, ce = (q & 127) >> 1;
      gload16(A + (size_t)(m0 + row) * K + kt * 64 + ce, As + i * 4096 + wid * 1024);
      gload16(B + (size_t)(n0 + row) * K + kt * 64 + ce, Bs + i * 4096 + wid * 1024);
    }
    __syncthreads();
    #pragma unroll
    for (int kk = 0; kk < 2; ++kk) {
      int co = (kk * 64 + g * 16) ^ (l7 << 4);
      f16x8 af[4], bf[4];
      #pragma unroll
      for (int fr = 0; fr < 4; ++fr)
        af[fr] = *(const f16x8*)(As + (wm * 64 + fr * 16 + c) * 128 + co);
      #pragma unroll
      for (int fn = 0; fn < 4; ++fn)
        bf[fn] = *(const f16x8*)(Bs + (wn * 64 + fn * 16 + c) * 128 + co);
      #pragma unroll
      for (int fr = 0; fr < 4; ++fr)
        #pragma unroll
        for (int fn = 0; fn < 4; ++fn)
          acc[fr][fn] = __builtin_amdgcn_mfma_f32_16x16x32_f16(af[fr], bf[fn], acc[fr][fn], 0, 0, 0);
    }
    __syncthreads();
  }

  #pragma unroll
  for (int fr = 0; fr < 4; ++fr) {
    int m = m0 + wm * 64 + fr * 16 + g * 4;
    #pragma unroll
    for (int fn = 0; fn < 4; ++fn) {
      int n = n0 + wn * 64 + fn * 16 + c;
      #pragma unroll
      for (int r = 0; r < 4; ++r)
        Cout[(size_t)(m + r) * 1024 + n] = acc[fr][fn][r];
    }
  }
}

// ---------------- flash attention (32x32 MFMA, 1 q-tile per block) ----------------
// 1024 blocks: o = qt_rank*64 + bh, qt = 15 - qt_rank (big tiles dispatched
// first for dynamic balance); bh & 7 fixes the XCD (o%8 = bh%8) so all 16
// blocks of a (b,h) share one XCD's L2 for K/V.
// 48KB LDS -> 3 blocks/CU resident; VGPR 120 -> 4 waves/SIMD OK.

__global__ __launch_bounds__(256) void attn(const f16* __restrict__ Q,
                                            const f16* __restrict__ Kh,
                                            const f16* __restrict__ Vt,
                                            const f16* __restrict__ U,
                                            const f16* __restrict__ Wt,
                                            f16* __restrict__ AO) {
  __shared__ __align__(16) char sm[49152];
  int tid = threadIdx.x, lane = tid & 63, wid = tid >> 6;
  int l31 = lane & 31, hi = lane >> 5;
  int o = blockIdx.x;
  int qt = 15 - (o >> 6);
  int bh = o & 63;
  int h = bh & 15, b = bh >> 4;
  int swzK = (lane & 15) << 4;
  int swzV = (lane & 7) << 4;

  // staging descriptors (pre-swizzled global sources, linear LDS dests)
  const f16* ksrc[4]; int kdst[4];
  #pragma unroll
  for (int i = 0; i < 4; ++i) {
    int p = i * 4096 + tid * 16;
    int row = p >> 8;
    int col = (p & 255) ^ ((row & 15) << 4);
    int ce = col >> 1;
    ksrc[i] = (ce < 64) ? (Kh + (size_t)(bh * 2048 + row) * 64 + ce)
                        : (Wt + (size_t)(h * 2048 + row) * 64 + (ce - 64));
    kdst[i] = i * 4096 + wid * 1024;
  }
  const f16* vsrc[2]; int vdst[2];
  #pragma unroll
  for (int i = 0; i < 2; ++i) {
    int p = i * 4096 + tid * 16;
    int row = p >> 7;
    int col = (p & 127) ^ ((row & 7) << 4);
    int ce = col >> 1;
    vsrc[i] = Vt + (size_t)(bh * 64 + row) * 2048 + ce;
    vdst[i] = i * 4096 + wid * 1024;
  }

  int qrow = qt * 128 + wid * 32 + l31;
  int ktmax = 2 * qt + 1;

  // Q' fragments: k = ks*16 + hi*8 + [0..8); ks 0-3 from Q, 4-7 from U
  f16x8 qf[8];
  {
    const f16* qp = Q + (size_t)(bh * 2048 + qrow) * 64 + hi * 8;
    const f16* up = U + (size_t)qrow * 64 + hi * 8;
    #pragma unroll
    for (int ks = 0; ks < 4; ++ks) {
      qf[ks]     = *(const f16x8*)(qp + ks * 16);
      qf[4 + ks] = *(const f16x8*)(up + ks * 16);
    }
  }

  float m_i = -1e30f, l_i = 0.0f;
  f32x16 accA = {}, accB = {};

  // prologue: stage tile 0 into buf 0
  #pragma unroll
  for (int i = 0; i < 4; ++i) gload16(ksrc[i], sm + kdst[i]);
  #pragma unroll
  for (int i = 0; i < 2; ++i) gload16(vsrc[i], sm + 32768 + vdst[i]);
  __syncthreads();

  for (int kt = 0; kt <= ktmax; ++kt) {
    int cur = kt & 1;
    char* Ks = sm + cur * 16384;
    char* Vs = sm + 32768 + cur * 8192;

    // issue next tile's staging first (hides under compute)
    if (kt < ktmax) {
      char* kb = sm + (cur ^ 1) * 16384;
      char* vb = sm + 32768 + (cur ^ 1) * 8192;
      #pragma unroll
      for (int i = 0; i < 4; ++i) gload16(ksrc[i] + (size_t)(kt + 1) * 4096, kb + kdst[i]);
      #pragma unroll
      for (int i = 0; i < 2; ++i) gload16(vsrc[i] + (size_t)(kt + 1) * 64, vb + vdst[i]);
    }

    // S^T = K' @ Q'^T : st0 = kv[0,32), st1 = kv[32,64); col = q = lane&31
    f32x16 st0 = {}, st1 = {};
    __builtin_amdgcn_s_setprio(1);
    #pragma unroll
    for (int ks = 0; ks < 8; ++ks) {
      int co = (ks * 32 + hi * 16) ^ swzK;
      f16x8 k0 = *(const f16x8*)(Ks + l31 * 256 + co);
      f16x8 k1 = *(const f16x8*)(Ks + (32 + l31) * 256 + co);
      st0 = __builtin_amdgcn_mfma_f32_32x32x16_f16(k0, qf[ks], st0, 0, 0, 0);
      st1 = __builtin_amdgcn_mfma_f32_32x32x16_f16(k1, qf[ks], st1, 0, 0, 0);
    }
    __builtin_amdgcn_s_setprio(0);

    int kv0 = kt * 64;
    if (kv0 + 63 > qt * 128 + wid * 32) {   // wave-uniform branch
      #pragma unroll
      for (int r = 0; r < 16; ++r) {
        int kvl = kv0 + (r & 3) + 8 * (r >> 2) + 4 * hi;
        if (kvl > qrow) st0[r] = -1e30f;
        if (kvl + 32 > qrow) st1[r] = -1e30f;
      }
    }

    // online softmax in exp2 space, defer-max (THR = 8)
    float pm = fmaxf(st0[0], st1[0]);
    #pragma unroll
    for (int r = 1; r < 16; ++r) pm = max3f(pm, st0[r], st1[r]);
    pm = fmaxf(pm, __shfl_xor(pm, 32, 64));
    if (!__all(pm <= m_i + 8.0f)) {
      float mnew = fmaxf(m_i, pm);
      float sc = __builtin_amdgcn_exp2f(m_i - mnew);
      l_i *= sc;
      accA *= sc;
      accB *= sc;
      m_i = mnew;
    }

    float ps = 0.0f;
    u32 pk0[8], pk1[8];
    #pragma unroll
    for (int j = 0; j < 8; ++j) {
      float a0 = __builtin_amdgcn_exp2f(st0[2 * j] - m_i);
      float a1 = __builtin_amdgcn_exp2f(st0[2 * j + 1] - m_i);
      float b0 = __builtin_amdgcn_exp2f(st1[2 * j] - m_i);
      float b1 = __builtin_amdgcn_exp2f(st1[2 * j + 1] - m_i);
      ps += (a0 + a1) + (b0 + b1);
      pk0[j] = pkrtz(a0, a1);
      pk1[j] = pkrtz(b0, b1);
    }
    ps += __shfl_xor(ps, 32, 64);
    l_i += ps;

    // redistribute P into PV B-fragments (kv = hi*8 + j within each 16-blk)
    pl32swap(pk0[0], pk0[2]); pl32swap(pk0[1], pk0[3]);
    pl32swap(pk0[4], pk0[6]); pl32swap(pk0[5], pk0[7]);
    pl32swap(pk1[0], pk1[2]); pl32swap(pk1[1], pk1[3]);
    pl32swap(pk1[4], pk1[6]); pl32swap(pk1[5], pk1[7]);

    // PV: O^T[d][q] += V'^T @ P^T ; accA = d[0,32), accB = d[32,64)
    __builtin_amdgcn_s_setprio(1);
    #pragma unroll
    for (int kb = 0; kb < 4; ++kb) {
      union { u32 w[4]; f16x8 v; } bf;
      if (kb == 0)      { bf.w[0] = pk0[0]; bf.w[1] = pk0[1]; bf.w[2] = pk0[2]; bf.w[3] = pk0[3]; }
      else if (kb == 1) { bf.w[0] = pk0[4]; bf.w[1] = pk0[5]; bf.w[2] = pk0[6]; bf.w[3] = pk0[7]; }
      else if (kb == 2) { bf.w[0] = pk1[0]; bf.w[1] = pk1[1]; bf.w[2] = pk1[2]; bf.w[3] = pk1[3]; }
      else              { bf.w[0] = pk1[4]; bf.w[1] = pk1[5]; bf.w[2] = pk1[6]; bf.w[3] = pk1[7]; }
      int co = (kb * 32 + hi * 16) ^ swzV;
      f16x8 v0 = *(const f16x8*)(Vs + l31 * 128 + co);
      f16x8 v1 = *(const f16x8*)(Vs + (32 + l31) * 128 + co);
      accA = __builtin_amdgcn_mfma_f32_32x32x16_f16(v0, bf.v, accA, 0, 0, 0);
      accB = __builtin_amdgcn_mfma_f32_32x32x16_f16(v1, bf.v, accB, 0, 0, 0);
    }
    __builtin_amdgcn_s_setprio(0);
    __syncthreads();
  }

  // epilogue: O[q][d] = acc^T / l ; d = (r&3) + 8*(r>>2) + 4*hi (+32 for accB)
  float inv = __builtin_amdgcn_rcpf(l_i);
  f16* aop = AO + (size_t)(b * 2048 + qrow) * 1024 + h * 64;
  #pragma unroll
  for (int u = 0; u < 4; ++u) {
    uint2 ov;
    ov.x = pkrtz(accA[4 * u] * inv, accA[4 * u + 1] * inv);
    ov.y = pkrtz(accA[4 * u + 2] * inv, accA[4 * u + 3] * inv);
    *(uint2*)(aop + 8 * u + 4 * hi) = ov;
    ov.x = pkrtz(accB[4 * u] * inv, accB[4 * u + 1] * inv);
    ov.y = pkrtz(accB[4 * u + 2] * inv, accB[4 * u + 3] * inv);
    *(uint2*)(aop + 32 + 8 * u + 4 * hi) = ov;
  }
}

// ---------------- launcher ----------------

extern "C" void kernel_launch(void* const* d_in, const int* in_sizes, int n_in,
                              void* d_out, int out_size, void* d_ws, size_t ws_size,
                              hipStream_t stream) {
  const float* x     = (const float*)d_in[0];
  const float* Wqkv  = (const float*)d_in[1];
  const float* Wout  = (const float*)d_in[2];
  const float* alpha = (const float*)d_in[3];
  const float* beta  = (const float*)d_in[4];

  char* ws = (char*)d_ws;
  f16* Xh    = (f16*)(ws);                  // 16 MiB  (later reused as AO)
  f16* Wqkvh = (f16*)(ws + 16777216);       // 6 MiB
  f16* Wouth = (f16*)(ws + 23068672);       // 2 MiB
  f16* Qh    = (f16*)(ws + 25165824);       // 16 MiB
  f16* Kh    = (f16*)(ws + 41943040);       // 16 MiB
  f16* Vt    = (f16*)(ws + 58720256);       // 16 MiB
  f16* U     = (f16*)(ws + 75497472);       // 256 KiB
  f16* Wt    = (f16*)(ws + 75759616);       // 4 MiB
  f16* AO    = Xh;

  cvt_f32_f16<<<4096, 256, 0, stream>>>(x, Xh, 8388608);
  cvt_f32_f16<<<1536, 256, 0, stream>>>(Wqkv, Wqkvh, 3145728);
  cvt_f32_f16<<<512, 256, 0, stream>>>(Wout, Wouth, 1048576);
  build_tables<<<256, 256, 0, stream>>>(alpha, beta, U, Wt);
  gemm_qkv<<<1536, 256, 0, stream>>>(Xh, Wqkvh, Qh, Kh, Vt);
  attn<<<1024, 256, 0, stream>>>(Qh, Kh, Vt, U, Wt, AO);
  gemm_out<<<512, 256, 0, stream>>>(AO, Wouth, (float*)d_out);
}

// Round 8
// 184.353 us; speedup vs baseline: 1.0463x; 1.0463x over previous
//
#include <hip/hip_runtime.h>
#include <cstdint>
#include <cstddef>

typedef _Float16 f16;
typedef f16 f16x8 __attribute__((ext_vector_type(8)));
typedef __fp16 fp16x2 __attribute__((ext_vector_type(2)));
typedef float f32x4 __attribute__((ext_vector_type(4)));
typedef float f32x16 __attribute__((ext_vector_type(16)));
typedef uint32_t u32;

// ---------------- helpers ----------------

__device__ __forceinline__ void gload16(const void* g, void* l) {
  __builtin_amdgcn_global_load_lds((const __attribute__((address_space(1))) void*)g,
                                   (__attribute__((address_space(3))) void*)l,
                                   16u, 0, 0u);
}

__device__ __forceinline__ u32 pkrtz(float a, float b) {
  union { fp16x2 v; u32 u; } t;
  t.v = __builtin_amdgcn_cvt_pkrtz(a, b);
  return t.u;
}

__device__ __forceinline__ u32 packh2(float a, float b) { return pkrtz(a, b); }

__device__ __forceinline__ float max3f(float a, float b, float c) {
  return fmaxf(fmaxf(a, b), c);
}

// exchange halves between a and b (used ONLY with distance>=8 from writes of
// its inputs -- VALU->permlane hazard; see R7 post-mortem)
__device__ __forceinline__ void pl32swap(u32& a, u32& b) {
  asm volatile("v_permlane32_swap_b32 %0, %1" : "+v"(a), "+v"(b));
}

// ---------------- fp32 -> fp16 convert ----------------

__global__ __launch_bounds__(256) void cvt_f32_f16(const float* __restrict__ in,
                                                   f16* __restrict__ out, int n) {
  int i = (blockIdx.x * 256 + threadIdx.x) * 8;
  if (i >= n) return;
  float4 a = *(const float4*)(in + i);
  float4 b = *(const float4*)(in + i + 4);
  f16x8 o;
  o[0] = (f16)a.x; o[1] = (f16)a.y; o[2] = (f16)a.z; o[3] = (f16)a.w;
  o[4] = (f16)b.x; o[5] = (f16)b.y; o[6] = (f16)b.z; o[7] = (f16)b.w;
  *(f16x8*)(out + i) = o;
}

// ---------------- bias factor tables ----------------
// U[t][2r] = log2e*cos(w_r t), U[t][2r+1] = log2e*sin(w_r t)   (2048 x 64)
// Wt[h][t][2r] = a*c - b*s, Wt[h][t][2r+1] = a*s + b*c         (16 x 2048 x 64)

__global__ __launch_bounds__(256) void build_tables(const float* __restrict__ alpha,
                                                    const float* __restrict__ beta,
                                                    f16* __restrict__ U,
                                                    f16* __restrict__ Wt) {
  int idx = blockIdx.x * 256 + threadIdx.x;   // t*32 + r
  int t = idx >> 5, r = idx & 31;
  float w = powf(10000.0f, -(float)r / 32.0f);
  float ang = w * (float)t;
  float c = cosf(ang), s = sinf(ang);
  const float L2E = 1.44269504089f;
  U[t * 64 + 2 * r]     = (f16)(c * L2E);
  U[t * 64 + 2 * r + 1] = (f16)(s * L2E);
  #pragma unroll
  for (int h = 0; h < 16; ++h) {
    float al = alpha[h * 32 + r], be = beta[h * 32 + r];
    Wt[(size_t)(h * 2048 + t) * 64 + 2 * r]     = (f16)(al * c - be * s);
    Wt[(size_t)(h * 2048 + t) * 64 + 2 * r + 1] = (f16)(al * s + be * c);
  }
}

// ---------------- GEMM1: qkv = X @ Wqkv^T, scatter into Q,K,Vt ----------------

__global__ __launch_bounds__(256) void gemm_qkv(const f16* __restrict__ A,
                                                const f16* __restrict__ B,
                                                f16* __restrict__ Q,
                                                f16* __restrict__ Kh,
                                                f16* __restrict__ Vt) {
  __shared__ __align__(16) char sm[32768];
  char* As = sm;
  char* Bs = sm + 16384;
  const int K = 1024;
  int tid = threadIdx.x;
  int lane = tid & 63, wid = tid >> 6;
  int bid = blockIdx.x;                      // 1536 blocks, XCD-chunked
  int id = (bid & 7) * 192 + (bid >> 3);
  int m0 = (id / 24) * 128, n0 = (id % 24) * 128;
  int wm = wid >> 1, wn = wid & 1;
  int c = lane & 15, g = lane >> 4, l7 = lane & 7;

  f32x4 acc[4][4] = {};

  for (int kt = 0; kt < K / 64; ++kt) {
    #pragma unroll
    for (int i = 0; i < 4; ++i) {
      int p = i * 4096 + tid * 16;
      int q = p ^ (((p >> 7) & 7) << 4);
      int row = q >> 7, ce = (q & 127) >> 1;
      gload16(A + (size_t)(m0 + row) * K + kt * 64 + ce, As + i * 4096 + wid * 1024);
      gload16(B + (size_t)(n0 + row) * K + kt * 64 + ce, Bs + i * 4096 + wid * 1024);
    }
    __syncthreads();
    #pragma unroll
    for (int kk = 0; kk < 2; ++kk) {
      int co = (kk * 64 + g * 16) ^ (l7 << 4);
      f16x8 af[4], bf[4];
      #pragma unroll
      for (int fr = 0; fr < 4; ++fr)
        af[fr] = *(const f16x8*)(As + (wm * 64 + fr * 16 + c) * 128 + co);
      #pragma unroll
      for (int fn = 0; fn < 4; ++fn)
        bf[fn] = *(const f16x8*)(Bs + (wn * 64 + fn * 16 + c) * 128 + co);
      #pragma unroll
      for (int fr = 0; fr < 4; ++fr)
        #pragma unroll
        for (int fn = 0; fn < 4; ++fn)
          acc[fr][fn] = __builtin_amdgcn_mfma_f32_16x16x32_f16(af[fr], bf[fn], acc[fr][fn], 0, 0, 0);
    }
    __syncthreads();
  }

  int which = n0 >> 10;
  #pragma unroll
  for (int fr = 0; fr < 4; ++fr) {
    int m = m0 + wm * 64 + fr * 16 + g * 4;
    int b = m >> 11, t = m & 2047;
    #pragma unroll
    for (int fn = 0; fn < 4; ++fn) {
      int n = n0 + wn * 64 + fn * 16 + c;
      int nf = n & 1023, hh = nf >> 6, d = nf & 63;
      if (which == 0) {
        #pragma unroll
        for (int r = 0; r < 4; ++r)
          Q[(size_t)((b * 16 + hh) * 2048 + (t + r)) * 64 + d] = (f16)(acc[fr][fn][r] * 0.180336880111f);
      } else if (which == 1) {
        #pragma unroll
        for (int r = 0; r < 4; ++r)
          Kh[(size_t)((b * 16 + hh) * 2048 + (t + r)) * 64 + d] = (f16)acc[fr][fn][r];
      } else {
        uint2 pk;
        pk.x = packh2(acc[fr][fn][0], acc[fr][fn][1]);
        pk.y = packh2(acc[fr][fn][2], acc[fr][fn][3]);
        *(uint2*)(Vt + (size_t)((b * 16 + hh) * 64 + d) * 2048 + t) = pk;
      }
    }
  }
}

// ---------------- GEMM2: out = AO @ Wout^T (fp32 out) ----------------

__global__ __launch_bounds__(256) void gemm_out(const f16* __restrict__ A,
                                                const f16* __restrict__ B,
                                                float* __restrict__ Cout) {
  __shared__ __align__(16) char sm[32768];
  char* As = sm;
  char* Bs = sm + 16384;
  const int K = 1024;
  int tid = threadIdx.x;
  int lane = tid & 63, wid = tid >> 6;
  int bid = blockIdx.x;                      // 512 blocks, XCD-chunked
  int id = (bid & 7) * 64 + (bid >> 3);
  int m0 = (id >> 3) * 128, n0 = (id & 7) * 128;
  int wm = wid >> 1, wn = wid & 1;
  int c = lane & 15, g = lane >> 4, l7 = lane & 7;

  f32x4 acc[4][4] = {};

  for (int kt = 0; kt < K / 64; ++kt) {
    #pragma unroll
    for (int i = 0; i < 4; ++i) {
      int p = i * 4096 + tid * 16;
      int q = p ^ (((p >> 7) & 7) << 4);
      int row = q >> 7, ce = (q & 127) >> 1;
      gload16(A + (size_t)(m0 + row) * K + kt * 64 + ce, As + i * 4096 + wid * 1024);
      gload16(B + (size_t)(n0 + row) * K + kt * 64 + ce, Bs + i * 4096 + wid * 1024);
    }
    __syncthreads();
    #pragma unroll
    for (int kk = 0; kk < 2; ++kk) {
      int co = (kk * 64 + g * 16) ^ (l7 << 4);
      f16x8 af[4], bf[4];
      #pragma unroll
      for (int fr = 0; fr < 4; ++fr)
        af[fr] = *(const f16x8*)(As + (wm * 64 + fr * 16 + c) * 128 + co);
      #pragma unroll
      for (int fn = 0; fn < 4; ++fn)
        bf[fn] = *(const f16x8*)(Bs + (wn * 64 + fn * 16 + c) * 128 + co);
      #pragma unroll
      for (int fr = 0; fr < 4; ++fr)
        #pragma unroll
        for (int fn = 0; fn < 4; ++fn)
          acc[fr][fn] = __builtin_amdgcn_mfma_f32_16x16x32_f16(af[fr], bf[fn], acc[fr][fn], 0, 0, 0);
    }
    __syncthreads();
  }

  #pragma unroll
  for (int fr = 0; fr < 4; ++fr) {
    int m = m0 + wm * 64 + fr * 16 + g * 4;
    #pragma unroll
    for (int fn = 0; fn < 4; ++fn) {
      int n = n0 + wn * 64 + fn * 16 + c;
      #pragma unroll
      for (int r = 0; r < 4; ++r)
        Cout[(size_t)(m + r) * 1024 + n] = acc[fr][fn][r];
    }
  }
}

// ---------------- flash attention (8 waves, q-tile 256) ----------------
// Block = 512 threads = 8 waves x 32 q-rows = 256 q-rows; kv-tile 64.
// Causal pairing: block p of each bh handles q-tiles {7-p, p} -> uniform
// 36 kv-iters. 256 blocks = exactly 1/CU; bh%8 pins XCD (K/V L2 affinity).
// Each staged K'/V tile feeds 256 q-rows (2x the reuse of R6).
// Cross-half reductions use __shfl_xor (proven); raw-asm permlane only for
// the P redistribution whose inputs are >=8 instructions upstream.

__global__ __launch_bounds__(512, 2) void attn(const f16* __restrict__ Q,
                                               const f16* __restrict__ Kh,
                                               const f16* __restrict__ Vt,
                                               const f16* __restrict__ U,
                                               const f16* __restrict__ Wt,
                                               f16* __restrict__ AO) {
  __shared__ __align__(16) char sm[49152];
  int tid = threadIdx.x, lane = tid & 63, wid = tid >> 6;
  int l31 = lane & 31, hi = lane >> 5;
  int o = blockIdx.x;
  int pr = o >> 6;                 // 0..3
  int bh = o & 63;
  int h = bh & 15, b = bh >> 4;
  int swzK = (lane & 15) << 4;
  int swzV = (lane & 7) << 4;

  // staging descriptors (pre-swizzled global sources, linear LDS dests)
  const f16* ksrc[2]; int kdst[2];
  #pragma unroll
  for (int i = 0; i < 2; ++i) {
    int p = i * 8192 + tid * 16;
    int row = p >> 8;
    int col = (p & 255) ^ ((row & 15) << 4);
    int ce = col >> 1;
    ksrc[i] = (ce < 64) ? (Kh + (size_t)(bh * 2048 + row) * 64 + ce)
                        : (Wt + (size_t)(h * 2048 + row) * 64 + (ce - 64));
    kdst[i] = i * 8192 + (tid >> 6) * 1024;
  }
  const f16* vsrc; int vdst;
  {
    int p = tid * 16;
    int row = p >> 7;
    int col = (p & 127) ^ ((row & 7) << 4);
    int ce = col >> 1;
    vsrc = Vt + (size_t)(bh * 64 + row) * 2048 + ce;
    vdst = (tid >> 6) * 1024;
  }

  #pragma unroll 1
  for (int pass = 0; pass < 2; ++pass) {
    int qt = pass ? pr : 7 - pr;
    int qrow = qt * 256 + wid * 32 + l31;
    int ktmax = 4 * qt + 3;

    // Q' fragments: k = ks*16 + hi*8 + [0..8); ks 0-3 from Q, 4-7 from U
    f16x8 qf[8];
    {
      const f16* qp = Q + (size_t)(bh * 2048 + qrow) * 64 + hi * 8;
      const f16* up = U + (size_t)qrow * 64 + hi * 8;
      #pragma unroll
      for (int ks = 0; ks < 4; ++ks) {
        qf[ks]     = *(const f16x8*)(qp + ks * 16);
        qf[4 + ks] = *(const f16x8*)(up + ks * 16);
      }
    }

    float m_i = -1e30f, l_i = 0.0f;
    f32x16 accA = {}, accB = {};

    // prologue: stage tile 0 into buf 0
    #pragma unroll
    for (int i = 0; i < 2; ++i) gload16(ksrc[i], sm + kdst[i]);
    gload16(vsrc, sm + 32768 + vdst);
    __syncthreads();

    for (int kt = 0; kt <= ktmax; ++kt) {
      int cur = kt & 1;
      char* Ks = sm + cur * 16384;
      char* Vs = sm + 32768 + cur * 8192;

      // issue next tile's staging first (hides under compute)
      if (kt < ktmax) {
        char* kb = sm + (cur ^ 1) * 16384;
        char* vb = sm + 32768 + (cur ^ 1) * 8192;
        #pragma unroll
        for (int i = 0; i < 2; ++i) gload16(ksrc[i] + (size_t)(kt + 1) * 4096, kb + kdst[i]);
        gload16(vsrc + (size_t)(kt + 1) * 64, vb + vdst);
      }

      // S^T = K' @ Q'^T : st0 = kv[0,32), st1 = kv[32,64); col = q = lane&31
      f32x16 st0 = {}, st1 = {};
      __builtin_amdgcn_s_setprio(1);
      #pragma unroll
      for (int ks = 0; ks < 8; ++ks) {
        int co = (ks * 32 + hi * 16) ^ swzK;
        f16x8 k0 = *(const f16x8*)(Ks + l31 * 256 + co);
        f16x8 k1 = *(const f16x8*)(Ks + (32 + l31) * 256 + co);
        st0 = __builtin_amdgcn_mfma_f32_32x32x16_f16(k0, qf[ks], st0, 0, 0, 0);
        st1 = __builtin_amdgcn_mfma_f32_32x32x16_f16(k1, qf[ks], st1, 0, 0, 0);
      }
      __builtin_amdgcn_s_setprio(0);

      int kv0 = kt * 64;
      if (kv0 + 63 > qt * 256 + wid * 32) {   // wave-uniform branch
        #pragma unroll
        for (int r = 0; r < 16; ++r) {
          int kvl = kv0 + (r & 3) + 8 * (r >> 2) + 4 * hi;
          if (kvl > qrow) st0[r] = -1e30f;
          if (kvl + 32 > qrow) st1[r] = -1e30f;
        }
      }

      // online softmax in exp2 space, defer-max (THR = 8)
      float pm = fmaxf(st0[0], st1[0]);
      #pragma unroll
      for (int r = 1; r < 16; ++r) pm = max3f(pm, st0[r], st1[r]);
      pm = fmaxf(pm, __shfl_xor(pm, 32, 64));
      if (!__all(pm <= m_i + 8.0f)) {
        float mnew = fmaxf(m_i, pm);
        float sc = __builtin_amdgcn_exp2f(m_i - mnew);
        l_i *= sc;
        accA *= sc;
        accB *= sc;
        m_i = mnew;
      }

      float ps = 0.0f;
      u32 pk0[8], pk1[8];
      #pragma unroll
      for (int j = 0; j < 8; ++j) {
        float a0 = __builtin_amdgcn_exp2f(st0[2 * j] - m_i);
        float a1 = __builtin_amdgcn_exp2f(st0[2 * j + 1] - m_i);
        float b0 = __builtin_amdgcn_exp2f(st1[2 * j] - m_i);
        float b1 = __builtin_amdgcn_exp2f(st1[2 * j + 1] - m_i);
        ps += (a0 + a1) + (b0 + b1);
        pk0[j] = pkrtz(a0, a1);
        pk1[j] = pkrtz(b0, b1);
      }
      ps += __shfl_xor(ps, 32, 64);
      l_i += ps;

      // redistribute P into PV B-fragments (kv = hi*8 + j within each 16-blk)
      pl32swap(pk0[0], pk0[2]); pl32swap(pk0[1], pk0[3]);
      pl32swap(pk0[4], pk0[6]); pl32swap(pk0[5], pk0[7]);
      pl32swap(pk1[0], pk1[2]); pl32swap(pk1[1], pk1[3]);
      pl32swap(pk1[4], pk1[6]); pl32swap(pk1[5], pk1[7]);

      // PV: O^T[d][q] += V'^T @ P^T ; accA = d[0,32), accB = d[32,64)
      __builtin_amdgcn_s_setprio(1);
      #pragma unroll
      for (int kb = 0; kb < 4; ++kb) {
        union { u32 w[4]; f16x8 v; } bf;
        if (kb == 0)      { bf.w[0] = pk0[0]; bf.w[1] = pk0[1]; bf.w[2] = pk0[2]; bf.w[3] = pk0[3]; }
        else if (kb == 1) { bf.w[0] = pk0[4]; bf.w[1] = pk0[5]; bf.w[2] = pk0[6]; bf.w[3] = pk0[7]; }
        else if (kb == 2) { bf.w[0] = pk1[0]; bf.w[1] = pk1[1]; bf.w[2] = pk1[2]; bf.w[3] = pk1[3]; }
        else              { bf.w[0] = pk1[4]; bf.w[1] = pk1[5]; bf.w[2] = pk1[6]; bf.w[3] = pk1[7]; }
        int co = (kb * 32 + hi * 16) ^ swzV;
        f16x8 v0 = *(const f16x8*)(Vs + l31 * 128 + co);
        f16x8 v1 = *(const f16x8*)(Vs + (32 + l31) * 128 + co);
        accA = __builtin_amdgcn_mfma_f32_32x32x16_f16(v0, bf.v, accA, 0, 0, 0);
        accB = __builtin_amdgcn_mfma_f32_32x32x16_f16(v1, bf.v, accB, 0, 0, 0);
      }
      __builtin_amdgcn_s_setprio(0);
      __syncthreads();
    }

    // epilogue: O[q][d] = acc^T / l ; d = (r&3) + 8*(r>>2) + 4*hi (+32 for accB)
    float inv = __builtin_amdgcn_rcpf(l_i);
    f16* aop = AO + (size_t)(b * 2048 + qrow) * 1024 + h * 64;
    #pragma unroll
    for (int u = 0; u < 4; ++u) {
      uint2 ov;
      ov.x = pkrtz(accA[4 * u] * inv, accA[4 * u + 1] * inv);
      ov.y = pkrtz(accA[4 * u + 2] * inv, accA[4 * u + 3] * inv);
      *(uint2*)(aop + 8 * u + 4 * hi) = ov;
      ov.x = pkrtz(accB[4 * u] * inv, accB[4 * u + 1] * inv);
      ov.y = pkrtz(accB[4 * u + 2] * inv, accB[4 * u + 3] * inv);
      *(uint2*)(aop + 32 + 8 * u + 4 * hi) = ov;
    }
  }
}

// ---------------- launcher ----------------

extern "C" void kernel_launch(void* const* d_in, const int* in_sizes, int n_in,
                              void* d_out, int out_size, void* d_ws, size_t ws_size,
                              hipStream_t stream) {
  const float* x     = (const float*)d_in[0];
  const float* Wqkv  = (const float*)d_in[1];
  const float* Wout  = (const float*)d_in[2];
  const float* alpha = (const float*)d_in[3];
  const float* beta  = (const float*)d_in[4];

  char* ws = (char*)d_ws;
  f16* Xh    = (f16*)(ws);                  // 16 MiB  (later reused as AO)
  f16* Wqkvh = (f16*)(ws + 16777216);       // 6 MiB
  f16* Wouth = (f16*)(ws + 23068672);       // 2 MiB
  f16* Qh    = (f16*)(ws + 25165824);       // 16 MiB
  f16* Kh    = (f16*)(ws + 41943040);       // 16 MiB
  f16* Vt    = (f16*)(ws + 58720256);       // 16 MiB
  f16* U     = (f16*)(ws + 75497472);       // 256 KiB
  f16* Wt    = (f16*)(ws + 75759616);       // 4 MiB
  f16* AO    = Xh;

  cvt_f32_f16<<<4096, 256, 0, stream>>>(x, Xh, 8388608);
  cvt_f32_f16<<<1536, 256, 0, stream>>>(Wqkv, Wqkvh, 3145728);
  cvt_f32_f16<<<512, 256, 0, stream>>>(Wout, Wouth, 1048576);
  build_tables<<<256, 256, 0, stream>>>(alpha, beta, U, Wt);
  gemm_qkv<<<1536, 256, 0, stream>>>(Xh, Wqkvh, Qh, Kh, Vt);
  attn<<<256, 512, 0, stream>>>(Qh, Kh, Vt, U, Wt, AO);
  gemm_out<<<512, 256, 0, stream>>>(AO, Wouth, (float*)d_out);
}